// Round 4
// baseline (256.394 us; speedup 1.0000x reference)
//
#include <hip/hip_runtime.h>

// Problem constants (from reference setup_inputs)
#define B_ 64
#define C_ 256
#define T_ 2048
#define EPS_ 1e-4f
#define NPC ((float)(B_ * T_))   // elements per channel = 131072

#define T4 (T_ / 4)              // 512 vec4 per row
#define CG_ 8                    // channels per stats slab (64 KiB contiguous)

// Norm kernel tiling: block = 16 channels x 16 t4 (=64 t), 32 batch rows
#define CTILE 16
#define T4TILE 16
#define BCHUNK 32

typedef float f4 __attribute__((ext_vector_type(4)));

// ---------------------------------------------------------------------------
// Kernel 1: slab stats. Grid = B_*(C_/CG_) = 2048 blocks of 256.
// Block (b, cg) reads ONE contiguous 64 KiB slab: channels cg*8..cg*8+7 of
// batch b. Per thread: 16 f4 loads, channel-uniform accumulation acc[i>>1].
// Reduction: LDS transpose [8ch][256] then 32-lane-group shuffle reduce.
//   partials layout: [sum: B_*C_][ssq: B_*C_]  (128 KB)
// ---------------------------------------------------------------------------
__global__ __launch_bounds__(256) void bntt_stats(const float* __restrict__ x,
                                                  float* __restrict__ partials) {
    const int bid = blockIdx.x;
    const int b   = bid >> 5;            // 64 batches
    const int cg  = bid & 31;            // 32 channel-groups of 8
    const int tid = threadIdx.x;
    const f4* p = (const f4*)(x + ((size_t)b * C_ + (size_t)cg * CG_) * T_);

    float sum[CG_], ssq[CG_];
    #pragma unroll
    for (int k = 0; k < CG_; ++k) { sum[k] = 0.0f; ssq[k] = 0.0f; }

    #pragma unroll
    for (int i = 0; i < 16; ++i) {       // slab = 4096 f4; channel = i>>1
        f4 v = p[tid + i * 256];
        const int k = i >> 1;
        sum[k] += v.x + v.y + v.z + v.w;
        ssq[k] += v.x * v.x + v.y * v.y + v.z * v.z + v.w * v.w;
    }

    // LDS transpose reduce: ls[k][tid], then 32 lanes per channel.
    __shared__ float ls[CG_][256];
    __shared__ float lq[CG_][256];
    #pragma unroll
    for (int k = 0; k < CG_; ++k) { ls[k][tid] = sum[k]; lq[k][tid] = ssq[k]; }
    __syncthreads();

    const int k = tid >> 5;              // channel 0..7
    const int j = tid & 31;              // lane within group
    float S = 0.0f, SS = 0.0f;
    #pragma unroll
    for (int m = 0; m < 8; ++m) {        // 256 values / 32 lanes
        S  += ls[k][j + m * 32];
        SS += lq[k][j + m * 32];
    }
    #pragma unroll
    for (int off = 16; off > 0; off >>= 1) {
        S  += __shfl_down(S, off);
        SS += __shfl_down(SS, off);
    }
    if (j == 0) {
        const size_t c = (size_t)cg * CG_ + k;
        partials[(size_t)b * C_ + c]                      = S;
        partials[(size_t)B_ * C_ + (size_t)b * C_ + c]    = SS;
    }
}

// ---------------------------------------------------------------------------
// Kernel 2: finalize + normalize, fused.
// Grid = 1024 blocks x 256 threads:
//   tile id = bid & 511  ->  c0 = (tile>>5)*16, t4base = (tile&31)*16
//   b-half  = bid >> 9   ->  b0 = half * 32
// Per block:
//   - stage gamma/beta [64 t x 16 c] slice into LDS (coalesced 64B rows)
//   - 128 threads reduce the 64 batch-partials for 16 channels (2-stage LDS)
//   - each thread owns one (c, t4): builds scale/shift f4 in registers once,
//     then streams 32 batch rows, unroll 8, f4 loads + non-temporal stores.
// ---------------------------------------------------------------------------
__global__ __launch_bounds__(256) void bntt_norm(const float* __restrict__ x,
                                                 const float* __restrict__ gamma,
                                                 const float* __restrict__ beta,
                                                 const float* __restrict__ partials,
                                                 float* __restrict__ out) {
    __shared__ float sg[64][17];         // gamma slice [t_local][c_local]
    __shared__ float sb[64][17];         // beta  slice
    __shared__ float psum[CTILE][8], psq[CTILE][8];
    __shared__ float smean[CTILE], sistd[CTILE];

    const int tid    = threadIdx.x;
    const int tile   = blockIdx.x & 511;
    const int c0     = (tile >> 5) * CTILE;      // 16 channel-tiles
    const int t4base = (tile & 31) * T4TILE;     // 32 t4-tiles
    const int b0     = (blockIdx.x >> 9) * BCHUNK;

    // stage gamma/beta slice: rows t = t4base*4 .. +63, cols c0 .. c0+15
    {
        const int cl  = tid & 15;
        const int tl0 = tid >> 4;                // 0..15
        const int tbase = t4base * 4;
        #pragma unroll
        for (int it = 0; it < 4; ++it) {
            const int tl = tl0 + it * 16;        // 0..63
            const size_t gi = (size_t)(tbase + tl) * C_ + (c0 + cl);
            sg[tl][cl] = gamma[gi];
            sb[tl][cl] = beta[gi];
        }
    }

    // stage-1 partials reduce: 128 threads, each sums 8 batches for 1 channel
    if (tid < 128) {
        const int cl = tid & 15;
        const int h  = tid >> 4;                 // 0..7
        const int c  = c0 + cl;
        float S = 0.0f, SS = 0.0f;
        #pragma unroll
        for (int m = 0; m < 8; ++m) {
            const size_t b = (size_t)(h * 8 + m);
            S  += partials[b * C_ + c];
            SS += partials[(size_t)B_ * C_ + b * C_ + c];
        }
        psum[cl][h] = S;
        psq[cl][h]  = SS;
    }
    __syncthreads();

    // stage-2: 16 threads finalize mean/istd
    if (tid < CTILE) {
        float S = 0.0f, SS = 0.0f;
        #pragma unroll
        for (int h = 0; h < 8; ++h) { S += psum[tid][h]; SS += psq[tid][h]; }
        const float mean = S / NPC;
        smean[tid] = mean;
        sistd[tid] = rsqrtf(SS / NPC - mean * mean + EPS_);
    }
    __syncthreads();

    // per-thread affine: thread = (ci, t4i)
    const int t4i = tid & 15;
    const int ci  = tid >> 4;
    const float mean = smean[ci];
    const float istd = sistd[ci];
    f4 sc, sh;
    #pragma unroll
    for (int j = 0; j < 4; ++j) {
        const int tl = t4i * 4 + j;
        const float s1 = sg[tl][ci] * istd;
        ((float*)&sc)[j] = s1;
        ((float*)&sh)[j] = fmaf(-mean, s1, sb[tl][ci]);
    }

    // stream 32 batch rows, deep unroll for load pipelining
    size_t idx = ((size_t)b0 * C_ + (c0 + ci)) * T4 + (t4base + t4i);
    const size_t step = (size_t)C_ * T4;         // one batch row
    #pragma unroll 8
    for (int b = 0; b < BCHUNK; ++b) {
        f4 xv = ((const f4*)x)[idx];
        f4 o;
        o.x = fmaf(xv.x, sc.x, sh.x);
        o.y = fmaf(xv.y, sc.y, sh.y);
        o.z = fmaf(xv.z, sc.z, sh.z);
        o.w = fmaf(xv.w, sc.w, sh.w);
        __builtin_nontemporal_store(o, &((f4*)out)[idx]);
        idx += step;
    }
}

// ---------------------------------------------------------------------------
// Fallback (ws < 128 KB): old 8-split stats (16 KB) + direct norm.
// ---------------------------------------------------------------------------
#define SPLITS 8
#define BPB (B_ / SPLITS)
__global__ __launch_bounds__(256) void bntt_stats_fb(const float* __restrict__ x,
                                                     float* __restrict__ partials) {
    const int c   = blockIdx.x & (C_ - 1);
    const int s   = blockIdx.x >> 8;
    const int tid = threadIdx.x;
    float sum = 0.0f, sumsq = 0.0f;
    const int b0 = s * BPB;
    #pragma unroll
    for (int b = 0; b < BPB; ++b) {
        const f4* p = (const f4*)(x + (size_t)(b0 + b) * (C_ * T_) + (size_t)c * T_);
        #pragma unroll
        for (int i = 0; i < T4 / 256; ++i) {
            f4 v = p[tid + i * 256];
            sum   += v.x + v.y + v.z + v.w;
            sumsq += v.x * v.x + v.y * v.y + v.z * v.z + v.w * v.w;
        }
    }
    #pragma unroll
    for (int off = 32; off > 0; off >>= 1) {
        sum   += __shfl_down(sum, off);
        sumsq += __shfl_down(sumsq, off);
    }
    __shared__ float ls2[4], lss2[4];
    const int wave = tid >> 6, lane = tid & 63;
    if (lane == 0) { ls2[wave] = sum; lss2[wave] = sumsq; }
    __syncthreads();
    if (tid == 0) {
        partials[s * C_ + c]               = ls2[0] + ls2[1] + ls2[2] + ls2[3];
        partials[SPLITS * C_ + s * C_ + c] = lss2[0] + lss2[1] + lss2[2] + lss2[3];
    }
}

__global__ __launch_bounds__(256) void bntt_norm_fb(const float* __restrict__ x,
                                                    const float* __restrict__ gamma,
                                                    const float* __restrict__ beta,
                                                    const float* __restrict__ partials,
                                                    float* __restrict__ out) {
    const int p   = (blockIdx.x & 511) * 256 + threadIdx.x;
    const int c   = p >> 9;
    const int t4  = p & (T4 - 1);
    const int t   = t4 * 4;
    const int b0  = (blockIdx.x >> 9) * BCHUNK;

    float S = 0.0f, SS = 0.0f;
    #pragma unroll
    for (int s = 0; s < SPLITS; ++s) {
        S  += partials[s * C_ + c];
        SS += partials[SPLITS * C_ + s * C_ + c];
    }
    const float mean = S / NPC;
    const float istd = rsqrtf(SS / NPC - mean * mean + EPS_);

    f4 sc, sh;
    #pragma unroll
    for (int j = 0; j < 4; ++j) {
        float g  = gamma[(size_t)(t + j) * C_ + c];
        float bb = beta [(size_t)(t + j) * C_ + c];
        float s1 = g * istd;
        ((float*)&sc)[j] = s1;
        ((float*)&sh)[j] = fmaf(-mean, s1, bb);
    }
    size_t idx = (size_t)(b0 * C_ + c) * T4 + t4;
    const size_t step = (size_t)C_ * T4;
    #pragma unroll 8
    for (int b = 0; b < BCHUNK; ++b) {
        f4 xv = ((const f4*)x)[idx];
        f4 o;
        o.x = fmaf(xv.x, sc.x, sh.x);
        o.y = fmaf(xv.y, sc.y, sh.y);
        o.z = fmaf(xv.z, sc.z, sh.z);
        o.w = fmaf(xv.w, sc.w, sh.w);
        __builtin_nontemporal_store(o, &((f4*)out)[idx]);
        idx += step;
    }
}

extern "C" void kernel_launch(void* const* d_in, const int* in_sizes, int n_in,
                              void* d_out, int out_size, void* d_ws, size_t ws_size,
                              hipStream_t stream) {
    const float* x     = (const float*)d_in[0];
    const float* gamma = (const float*)d_in[1];
    const float* beta  = (const float*)d_in[2];
    float* out = (float*)d_out;
    float* partials = (float*)d_ws;

    const int ngrid = (C_ / CTILE) * (T4 / T4TILE) * (B_ / BCHUNK);  // 1024

    if (ws_size >= (size_t)2 * B_ * C_ * sizeof(float)) {            // 128 KB
        bntt_stats<<<B_ * (C_ / CG_), 256, 0, stream>>>(x, partials);
        bntt_norm<<<ngrid, 256, 0, stream>>>(x, gamma, beta, partials, out);
    } else {
        bntt_stats_fb<<<C_ * SPLITS, 256, 0, stream>>>(x, partials);
        bntt_norm_fb<<<ngrid, 256, 0, stream>>>(x, gamma, beta, partials, out);
    }
}